// Round 3
// baseline (290.265 us; speedup 1.0000x reference)
//
#include <hip/hip_runtime.h>
#include <hip/hip_bf16.h>

typedef __attribute__((ext_vector_type(8))) short bf16x8;
typedef __attribute__((ext_vector_type(4))) float f32x4;

__device__ inline ushort f2bf(float f) {
    union { float f; unsigned u; } x; x.f = f;
    unsigned u = x.u;
    u += 0x7fffu + ((u >> 16) & 1u);   // round-to-nearest-even
    return (ushort)(u >> 16);
}

// feat (B,C,H,W) f32 -> featT (B,H,W,C) bf16
__global__ void prep_feat_k(const float* __restrict__ feat, ushort* __restrict__ featT) {
    int idx = blockIdx.x * 256 + threadIdx.x;
    if (idx >= 2 * 96 * 96 * 64) return;
    int c = idx & 63;
    int rest = idx >> 6;
    int x = rest % 96; rest /= 96;
    int y = rest % 96;
    int b = rest / 96;
    featT[idx] = f2bf(feat[((b * 64 + c) * 96 + y) * 96 + x]);
}

// Weights f32 (K,N) -> bf16 B-fragment layout [nt][kt][lane][8]
// mode 0: layer-1 with k-permutation (k = tap*64+c  <-  src row c*9+tap), K=580 pad 608
// mode 1: plain K=256
// mode 2: W4 (256,1), N padded to 16 (cols 1..15 zero)
__global__ void prep_w_k(const float* __restrict__ W, ushort* __restrict__ Wp,
                         int NT, int NKT, int Nstride, int mode) {
    int idx = blockIdx.x * 256 + threadIdx.x;
    if (idx >= NT * NKT * 64) return;
    int lane = idx & 63;
    int kt = (idx >> 6) % NKT;
    int nt = idx / (64 * NKT);
    int n = nt * 16 + (lane & 15);
    int kbase = kt * 32 + (lane >> 4) * 8;
    ushort o[8];
    #pragma unroll
    for (int i = 0; i < 8; ++i) {
        int k = kbase + i;
        float v = 0.0f;
        if (mode == 0) {
            if (k < 576) { int tap = k >> 6, c = k & 63; v = W[(c * 9 + tap) * Nstride + n]; }
            else if (k < 580) v = W[k * Nstride + n];
        } else if (mode == 1) {
            v = W[k * Nstride + n];
        } else {
            v = (n == 0) ? W[k] : 0.0f;
        }
        o[i] = f2bf(v);
    }
    *reinterpret_cast<uint4*>(Wp + (size_t)idx * 8) = *reinterpret_cast<const uint4*>(o);
}

// Block: 512 threads (8 waves), 32 queries -> 128 MLP rows (8 row-tiles of 16).
// Wave w owns column tiles {2w, 2w+1} -> each B fragment read ONCE per block.
// Layer-1 (K=608, 19 k-tiles) staged through a 40KB chunk buffer in 4 phases,
// aliased with the 64KB inter-layer activation buffer.
__global__ __launch_bounds__(512, 4) void liif_main(
    const float* __restrict__ coord, const float* __restrict__ cell,
    const ushort* __restrict__ featT,
    const ushort* __restrict__ W0p, const ushort* __restrict__ W1p,
    const ushort* __restrict__ W2p, const ushort* __restrict__ W3p,
    const ushort* __restrict__ W4p,
    const float* __restrict__ b0, const float* __restrict__ b1,
    const float* __restrict__ b2, const float* __restrict__ b3,
    const float* __restrict__ b4, float* __restrict__ out)
{
    // acts layout:  ((rt*8 + kt)*64 + sw)*8      rt 0..7, kt 0..7  (65536 B)
    // chunk layout: ((rt*5 + i )*64 + sw)*8      rt 0..7, i  0..4  (40960 B, aliased)
    __shared__ ushort buf[8 * 8 * 64 * 8];
    __shared__ float pred_lds[128];
    __shared__ float area_lds[128];

    const int t = threadIdx.x;
    const int lane = t & 63;
    const int w = t >> 6;
    const int swl = lane ^ ((lane >> 3) & 3);

    // ---------------- per-thread gather setup (4 threads per row) ----------------
    const int r = t >> 2, sub = t & 3;          // r 0..127
    const int qi = r >> 2, s = r & 3;           // row = 4*qi + shift s
    const int gq = blockIdx.x * 32 + qi;        // = b*Q + q
    const int bidx = gq >> 15;                  // Q = 32768
    int iy, ix;
    float rel0, rel1, rc0, rc1;
    {
        const float vx = (s & 2) ? 1.0f : -1.0f;
        const float vy = (s & 1) ? 1.0f : -1.0f;
        const float rxf = (float)(1.0 / 96.0);
        const float lo = (float)(-1.0 + 1e-6);
        const float hi = (float)(1.0 - 1e-6);
        float c0 = coord[gq * 2 + 0], c1 = coord[gq * 2 + 1];
        float cl0 = cell[gq * 2 + 0], cl1 = cell[gq * 2 + 1];
        float sc0 = fminf(fmaxf(__fadd_rn(__fadd_rn(c0, vx * rxf), 1e-6f), lo), hi);
        float sc1 = fminf(fmaxf(__fadd_rn(__fadd_rn(c1, vy * rxf), 1e-6f), lo), hi);
        float fy = __fmul_rn(__fadd_rn(__fmul_rn(__fadd_rn(sc0, 1.0f), 96.0f), -1.0f), 0.5f);
        float fx = __fmul_rn(__fadd_rn(__fmul_rn(__fadd_rn(sc1, 1.0f), 96.0f), -1.0f), 0.5f);
        iy = (int)rintf(fy); iy = iy < 0 ? 0 : (iy > 95 ? 95 : iy);
        ix = (int)rintf(fx); ix = ix < 0 ? 0 : (ix > 95 ? 95 : ix);
        float qc0 = (iy + 0.5f) * (float)(2.0 / 96.0) - 1.0f;
        float qc1 = (ix + 0.5f) * (float)(2.0 / 96.0) - 1.0f;
        rel0 = (c0 - qc0) * 96.0f;
        rel1 = (c1 - qc1) * 96.0f;
        rc0 = cl0 * 96.0f; rc1 = cl1 * 96.0f;
        if (sub == 0) area_lds[r] = fabsf(rel0 * rel1) + 1e-9f;
    }
    const int g_rt = r >> 4;                    // row-tile this thread gathers for
    const int g_slot = (r & 15) + (sub << 4);
    const int g_sw = g_slot ^ ((g_slot >> 3) & 3);
    const ushort* fb = featT + (size_t)bidx * 96 * 96 * 64;

    // ---------------- layer 1: 4 chunked phases of (gather -> mfma) ----------------
    f32x4 acc[8][2];
    {
        float bv0 = b0[(w * 2 + 0) * 16 + (lane & 15)];
        float bv1 = b0[(w * 2 + 1) * 16 + (lane & 15)];
        #pragma unroll
        for (int rt = 0; rt < 8; ++rt) {
            acc[rt][0][0] = bv0; acc[rt][0][1] = bv0; acc[rt][0][2] = bv0; acc[rt][0][3] = bv0;
            acc[rt][1][0] = bv1; acc[rt][1][1] = bv1; acc[rt][1][2] = bv1; acc[rt][1][3] = bv1;
        }
    }
    #pragma unroll 1
    for (int p = 0; p < 4; ++p) {
        const int nkt = (p == 3) ? 4 : 5;
        // gather this chunk
        #pragma unroll
        for (int i = 0; i < 5; ++i) {
            int kt = p * 5 + i;
            if (i >= nkt) break;
            uint4 val = make_uint4(0, 0, 0, 0);
            if (kt < 18) {
                int j = (kt << 2) + sub;        // chunk index: k = 8j.., tap = j>>3
                int tap = j >> 3;
                int cc = (j & 7) << 3;
                int yy = iy + (tap / 3) - 1;
                int xx = ix + (tap % 3) - 1;
                if (yy >= 0 && yy < 96 && xx >= 0 && xx < 96)
                    val = *reinterpret_cast<const uint4*>(fb + ((yy * 96 + xx) * 64 + cc));
            } else if (sub == 0) {              // extras: rel0, rel1, rel_cell, zero-pad
                ushort ex[8] = {0, 0, 0, 0, 0, 0, 0, 0};
                ex[0] = f2bf(rel0); ex[1] = f2bf(rel1);
                ex[2] = f2bf(rc0);  ex[3] = f2bf(rc1);
                val = *reinterpret_cast<const uint4*>(ex);
            }
            *reinterpret_cast<uint4*>(&buf[((g_rt * 5 + i) * 64 + g_sw) * 8]) = val;
        }
        __syncthreads();
        // mfma this chunk
        #pragma unroll 1
        for (int i = 0; i < nkt; ++i) {
            int kt = p * 5 + i;
            bf16x8 b0f = *reinterpret_cast<const bf16x8*>(W0p + (((size_t)(w * 2 + 0) * 19 + kt) * 64 + lane) * 8);
            bf16x8 b1f = *reinterpret_cast<const bf16x8*>(W0p + (((size_t)(w * 2 + 1) * 19 + kt) * 64 + lane) * 8);
            #pragma unroll
            for (int rt = 0; rt < 8; ++rt) {
                bf16x8 a = *reinterpret_cast<const bf16x8*>(buf + ((rt * 5 + i) * 64 + swl) * 8);
                acc[rt][0] = __builtin_amdgcn_mfma_f32_16x16x32_bf16(a, b0f, acc[rt][0], 0, 0, 0);
                acc[rt][1] = __builtin_amdgcn_mfma_f32_16x16x32_bf16(a, b1f, acc[rt][1], 0, 0, 0);
            }
        }
        __syncthreads();
    }

    // ---------------- store acts + layers 2..4 ----------------
    #pragma unroll 1
    for (int layer = 0; layer < 3; ++layer) {
        // store previous acc as bf16 acts (relu) into fragment layout
        #pragma unroll
        for (int rt = 0; rt < 8; ++rt)
            #pragma unroll
            for (int ct = 0; ct < 2; ++ct) {
                int col = (w * 2 + ct) * 16 + (lane & 15);
                int kt = col >> 5;
                int chk = (col & 31) >> 3;
                #pragma unroll
                for (int j = 0; j < 4; ++j) {
                    int rowm = ((lane >> 4) << 2) + j;
                    int slot = rowm + (chk << 4);
                    int sw = slot ^ ((slot >> 3) & 3);
                    buf[((rt * 8 + kt) * 64 + sw) * 8 + (col & 7)] =
                        f2bf(fmaxf(acc[rt][ct][j], 0.0f));
                }
            }
        __syncthreads();
        const ushort* Wp = (layer == 0) ? W1p : (layer == 1) ? W2p : W3p;
        const float* bias = (layer == 0) ? b1 : (layer == 1) ? b2 : b3;
        float bv0 = bias[(w * 2 + 0) * 16 + (lane & 15)];
        float bv1 = bias[(w * 2 + 1) * 16 + (lane & 15)];
        #pragma unroll
        for (int rt = 0; rt < 8; ++rt) {
            acc[rt][0][0] = bv0; acc[rt][0][1] = bv0; acc[rt][0][2] = bv0; acc[rt][0][3] = bv0;
            acc[rt][1][0] = bv1; acc[rt][1][1] = bv1; acc[rt][1][2] = bv1; acc[rt][1][3] = bv1;
        }
        #pragma unroll 1
        for (int kt = 0; kt < 8; ++kt) {
            bf16x8 b0f = *reinterpret_cast<const bf16x8*>(Wp + (((size_t)(w * 2 + 0) * 8 + kt) * 64 + lane) * 8);
            bf16x8 b1f = *reinterpret_cast<const bf16x8*>(Wp + (((size_t)(w * 2 + 1) * 8 + kt) * 64 + lane) * 8);
            #pragma unroll
            for (int rt = 0; rt < 8; ++rt) {
                bf16x8 a = *reinterpret_cast<const bf16x8*>(buf + ((rt * 8 + kt) * 64 + swl) * 8);
                acc[rt][0] = __builtin_amdgcn_mfma_f32_16x16x32_bf16(a, b0f, acc[rt][0], 0, 0, 0);
                acc[rt][1] = __builtin_amdgcn_mfma_f32_16x16x32_bf16(a, b1f, acc[rt][1], 0, 0, 0);
            }
        }
        __syncthreads();
    }
    // store layer-4 acts
    #pragma unroll
    for (int rt = 0; rt < 8; ++rt)
        #pragma unroll
        for (int ct = 0; ct < 2; ++ct) {
            int col = (w * 2 + ct) * 16 + (lane & 15);
            int kt = col >> 5;
            int chk = (col & 31) >> 3;
            #pragma unroll
            for (int j = 0; j < 4; ++j) {
                int rowm = ((lane >> 4) << 2) + j;
                int slot = rowm + (chk << 4);
                int sw = slot ^ ((slot >> 3) & 3);
                buf[((rt * 8 + kt) * 64 + sw) * 8 + (col & 7)] =
                    f2bf(fmaxf(acc[rt][ct][j], 0.0f));
            }
        }
    __syncthreads();

    // ---------------- layer 5: 256 -> 1 (wave w handles row-tile w) ----------------
    {
        float b4v = b4[0];
        f32x4 a5;
        a5[0] = b4v; a5[1] = b4v; a5[2] = b4v; a5[3] = b4v;
        #pragma unroll
        for (int kt = 0; kt < 8; ++kt) {
            bf16x8 bb = *reinterpret_cast<const bf16x8*>(W4p + ((size_t)kt * 64 + lane) * 8);
            bf16x8 aa = *reinterpret_cast<const bf16x8*>(buf + ((w * 8 + kt) * 64 + swl) * 8);
            a5 = __builtin_amdgcn_mfma_f32_16x16x32_bf16(aa, bb, a5, 0, 0, 0);
        }
        if ((lane & 15) == 0) {
            #pragma unroll
            for (int j = 0; j < 4; ++j)
                pred_lds[w * 16 + ((lane >> 4) << 2) + j] = a5[j];
        }
    }
    __syncthreads();

    // ---------------- local-ensemble combine (diagonal area swap) ----------------
    if (t < 32) {
        int oq = blockIdx.x * 32 + t;
        float p0 = pred_lds[t * 4 + 0], p1 = pred_lds[t * 4 + 1];
        float p2 = pred_lds[t * 4 + 2], p3 = pred_lds[t * 4 + 3];
        float a0 = area_lds[t * 4 + 0], a1 = area_lds[t * 4 + 1];
        float a2 = area_lds[t * 4 + 2], a3 = area_lds[t * 4 + 3];
        float tot = a0 + a1 + a2 + a3;
        out[oq] = (p0 * a3 + p1 * a2 + p2 * a1 + p3 * a0) / tot;
    }
}

extern "C" void kernel_launch(void* const* d_in, const int* in_sizes, int n_in,
                              void* d_out, int out_size, void* d_ws, size_t ws_size,
                              hipStream_t stream) {
    const float* feat  = (const float*)d_in[0];
    const float* coord = (const float*)d_in[1];
    const float* cell  = (const float*)d_in[2];
    const float* W0 = (const float*)d_in[3];
    const float* b0 = (const float*)d_in[4];
    const float* W1 = (const float*)d_in[5];
    const float* b1 = (const float*)d_in[6];
    const float* W2 = (const float*)d_in[7];
    const float* b2 = (const float*)d_in[8];
    const float* W3 = (const float*)d_in[9];
    const float* b3 = (const float*)d_in[10];
    const float* W4 = (const float*)d_in[11];
    const float* b4 = (const float*)d_in[12];
    float* out = (float*)d_out;

    ushort* featT = (ushort*)d_ws;          // 2*96*96*64      = 1179648 elems
    ushort* W0p = featT + 1179648;          // 16*19*64*8      = 155648
    ushort* W1p = W0p + 155648;             // 16*8*64*8       = 65536
    ushort* W2p = W1p + 65536;
    ushort* W3p = W2p + 65536;
    ushort* W4p = W3p + 65536;              // 1*8*64*8        = 4096

    prep_feat_k<<<4608, 256, 0, stream>>>(feat, featT);
    prep_w_k<<<76, 256, 0, stream>>>(W0, W0p, 16, 19, 256, 0);
    prep_w_k<<<32, 256, 0, stream>>>(W1, W1p, 16, 8, 256, 1);
    prep_w_k<<<32, 256, 0, stream>>>(W2, W2p, 16, 8, 256, 1);
    prep_w_k<<<32, 256, 0, stream>>>(W3, W3p, 16, 8, 256, 1);
    prep_w_k<<<2, 256, 0, stream>>>(W4, W4p, 1, 8, 1, 2);
    liif_main<<<2048, 512, 0, stream>>>(coord, cell, featT, W0p, W1p, W2p, W3p, W4p,
                                        b0, b1, b2, b3, b4, out);
}

// Round 4
// 227.749 us; speedup vs baseline: 1.2745x; 1.2745x over previous
//
#include <hip/hip_runtime.h>
#include <hip/hip_bf16.h>

typedef __attribute__((ext_vector_type(8))) short bf16x8;
typedef __attribute__((ext_vector_type(4))) float f32x4;

__device__ inline ushort f2bf(float f) {
    union { float f; unsigned u; } x; x.f = f;
    unsigned u = x.u;
    u += 0x7fffu + ((u >> 16) & 1u);   // round-to-nearest-even
    return (ushort)(u >> 16);
}

// feat (B,C,H,W) f32 -> featT (B,H,W,C) bf16
__global__ void prep_feat_k(const float* __restrict__ feat, ushort* __restrict__ featT) {
    int idx = blockIdx.x * 256 + threadIdx.x;
    if (idx >= 2 * 96 * 96 * 64) return;
    int c = idx & 63;
    int rest = idx >> 6;
    int x = rest % 96; rest /= 96;
    int y = rest % 96;
    int b = rest / 96;
    featT[idx] = f2bf(feat[((b * 64 + c) * 96 + y) * 96 + x]);
}

// Weights f32 (K,N) -> bf16 B-fragment layout [nt][kt][lane][8]
// mode 0: layer-1 with k-permutation (k = tap*64+c  <-  src row c*9+tap), K=580 pad 608
// mode 1: plain K=256
// mode 2: W4 (256,1), N padded to 16 (cols 1..15 zero)
__global__ void prep_w_k(const float* __restrict__ W, ushort* __restrict__ Wp,
                         int NT, int NKT, int Nstride, int mode) {
    int idx = blockIdx.x * 256 + threadIdx.x;
    if (idx >= NT * NKT * 64) return;
    int lane = idx & 63;
    int kt = (idx >> 6) % NKT;
    int nt = idx / (64 * NKT);
    int n = nt * 16 + (lane & 15);
    int kbase = kt * 32 + (lane >> 4) * 8;
    ushort o[8];
    #pragma unroll
    for (int i = 0; i < 8; ++i) {
        int k = kbase + i;
        float v = 0.0f;
        if (mode == 0) {
            if (k < 576) { int tap = k >> 6, c = k & 63; v = W[(c * 9 + tap) * Nstride + n]; }
            else if (k < 580) v = W[k * Nstride + n];
        } else if (mode == 1) {
            v = W[k * Nstride + n];
        } else {
            v = (n == 0) ? W[k] : 0.0f;
        }
        o[i] = f2bf(v);
    }
    *reinterpret_cast<uint4*>(Wp + (size_t)idx * 8) = *reinterpret_cast<const uint4*>(o);
}

// Block: 256 threads (4 waves), 16 queries -> 64 MLP rows (4 row-tiles of 16).
// Wave w owns column tiles {4w..4w+3}; acc[4][4] (round-0 register structure,
// proven no-spill). LDS cut 78KB -> 33KB by staging layer-1's 19 k-tiles
// through the 32KB activation buffer in 3 phases (8+8+3), so launch_bounds
// (256,3) gets 3 blocks/CU (12 waves/CU) with a 168-reg budget >= 152 used.
__global__ __launch_bounds__(256, 3) void liif_main(
    const float* __restrict__ coord, const float* __restrict__ cell,
    const ushort* __restrict__ featT,
    const ushort* __restrict__ W0p, const ushort* __restrict__ W1p,
    const ushort* __restrict__ W2p, const ushort* __restrict__ W3p,
    const ushort* __restrict__ W4p,
    const float* __restrict__ b0, const float* __restrict__ b1,
    const float* __restrict__ b2, const float* __restrict__ b3,
    const float* __restrict__ b4, float* __restrict__ out)
{
    // act layout:   ((rt*8 + kt)*64 + sw)*8   rt 0..3, kt 0..7   (32768 B)
    // chunk layout: ((rt*8 + i )*64 + sw)*8   rt 0..3, i  0..7   (same buffer)
    __shared__ ushort buf[4 * 8 * 64 * 8];
    __shared__ float pred_lds[64];
    __shared__ float area_lds[64];

    const int t = threadIdx.x;
    const int lane = t & 63;
    const int w = t >> 6;
    const int swl = lane ^ ((lane >> 3) & 3);

    // ---------------- per-thread gather setup (4 threads per row) ----------------
    const int r = t >> 2, sub = t & 3;          // r 0..63
    const int qi = r >> 2, s = r & 3;           // row = 4*qi + shift s
    const int gq = blockIdx.x * 16 + qi;        // = b*Q + q
    const int bidx = gq >> 15;                  // Q = 32768
    int iy, ix;
    float rel0, rel1, rc0, rc1;
    {
        const float vx = (s & 2) ? 1.0f : -1.0f;
        const float vy = (s & 1) ? 1.0f : -1.0f;
        const float rxf = (float)(1.0 / 96.0);
        const float lo = (float)(-1.0 + 1e-6);
        const float hi = (float)(1.0 - 1e-6);
        float c0 = coord[gq * 2 + 0], c1 = coord[gq * 2 + 1];
        float cl0 = cell[gq * 2 + 0], cl1 = cell[gq * 2 + 1];
        float sc0 = fminf(fmaxf(__fadd_rn(__fadd_rn(c0, vx * rxf), 1e-6f), lo), hi);
        float sc1 = fminf(fmaxf(__fadd_rn(__fadd_rn(c1, vy * rxf), 1e-6f), lo), hi);
        float fy = __fmul_rn(__fadd_rn(__fmul_rn(__fadd_rn(sc0, 1.0f), 96.0f), -1.0f), 0.5f);
        float fx = __fmul_rn(__fadd_rn(__fmul_rn(__fadd_rn(sc1, 1.0f), 96.0f), -1.0f), 0.5f);
        iy = (int)rintf(fy); iy = iy < 0 ? 0 : (iy > 95 ? 95 : iy);
        ix = (int)rintf(fx); ix = ix < 0 ? 0 : (ix > 95 ? 95 : ix);
        float qc0 = (iy + 0.5f) * (float)(2.0 / 96.0) - 1.0f;
        float qc1 = (ix + 0.5f) * (float)(2.0 / 96.0) - 1.0f;
        rel0 = (c0 - qc0) * 96.0f;
        rel1 = (c1 - qc1) * 96.0f;
        rc0 = cl0 * 96.0f; rc1 = cl1 * 96.0f;
        if (sub == 0) area_lds[r] = fabsf(rel0 * rel1) + 1e-9f;
    }
    const int g_rt = r >> 4;                    // row-tile this thread gathers for
    const int g_slot = (r & 15) + (sub << 4);
    const int g_sw = g_slot ^ ((g_slot >> 3) & 3);
    const ushort* fb = featT + (size_t)bidx * 96 * 96 * 64;

    // ---------------- layer 1: 3 chunked phases of (gather -> mfma) ----------------
    f32x4 acc[4][4];
    #pragma unroll
    for (int ct = 0; ct < 4; ++ct) {
        float bv = b0[(w * 4 + ct) * 16 + (lane & 15)];
        #pragma unroll
        for (int rt = 0; rt < 4; ++rt) {
            acc[rt][ct][0] = bv; acc[rt][ct][1] = bv;
            acc[rt][ct][2] = bv; acc[rt][ct][3] = bv;
        }
    }
    #pragma unroll 1
    for (int p = 0; p < 3; ++p) {
        const int nkt = (p == 2) ? 3 : 8;
        // gather this chunk into buf
        #pragma unroll
        for (int i = 0; i < 8; ++i) {
            if (i >= nkt) break;
            int kt = p * 8 + i;
            uint4 val = make_uint4(0, 0, 0, 0);
            if (kt < 18) {
                int j = (kt << 2) + sub;        // chunk index: k = 8j.., tap = j>>3
                int tap = j >> 3;
                int cc = (j & 7) << 3;
                int yy = iy + (tap / 3) - 1;
                int xx = ix + (tap % 3) - 1;
                if (yy >= 0 && yy < 96 && xx >= 0 && xx < 96)
                    val = *reinterpret_cast<const uint4*>(fb + ((yy * 96 + xx) * 64 + cc));
            } else if (sub == 0) {              // extras: rel0, rel1, rel_cell, zero-pad
                ushort ex[8] = {0, 0, 0, 0, 0, 0, 0, 0};
                ex[0] = f2bf(rel0); ex[1] = f2bf(rel1);
                ex[2] = f2bf(rc0);  ex[3] = f2bf(rc1);
                val = *reinterpret_cast<const uint4*>(ex);
            }
            *reinterpret_cast<uint4*>(&buf[((g_rt * 8 + i) * 64 + g_sw) * 8]) = val;
        }
        __syncthreads();
        // mfma this chunk
        #pragma unroll 1
        for (int i = 0; i < nkt; ++i) {
            int kt = p * 8 + i;
            bf16x8 bfr[4];
            #pragma unroll
            for (int ct = 0; ct < 4; ++ct)
                bfr[ct] = *reinterpret_cast<const bf16x8*>(W0p + (((size_t)(w * 4 + ct) * 19 + kt) * 64 + lane) * 8);
            #pragma unroll
            for (int rt = 0; rt < 4; ++rt) {
                bf16x8 a = *reinterpret_cast<const bf16x8*>(buf + ((rt * 8 + i) * 64 + swl) * 8);
                #pragma unroll
                for (int ct = 0; ct < 4; ++ct)
                    acc[rt][ct] = __builtin_amdgcn_mfma_f32_16x16x32_bf16(a, bfr[ct], acc[rt][ct], 0, 0, 0);
            }
        }
        __syncthreads();
    }

    // ---------------- store acts + layers 2..4 ----------------
    #pragma unroll 1
    for (int layer = 0; layer < 3; ++layer) {
        // store previous acc as bf16 acts (relu) into fragment layout
        #pragma unroll
        for (int rt = 0; rt < 4; ++rt)
            #pragma unroll
            for (int ct = 0; ct < 4; ++ct) {
                int col = (w * 4 + ct) * 16 + (lane & 15);
                int kt = col >> 5;
                int chk = (col & 31) >> 3;
                #pragma unroll
                for (int j = 0; j < 4; ++j) {
                    int rowm = ((lane >> 4) << 2) + j;
                    int slot = rowm + (chk << 4);
                    int sw = slot ^ ((slot >> 3) & 3);
                    buf[((rt * 8 + kt) * 64 + sw) * 8 + (col & 7)] =
                        f2bf(fmaxf(acc[rt][ct][j], 0.0f));
                }
            }
        __syncthreads();
        const ushort* Wp = (layer == 0) ? W1p : (layer == 1) ? W2p : W3p;
        const float* bias = (layer == 0) ? b1 : (layer == 1) ? b2 : b3;
        #pragma unroll
        for (int ct = 0; ct < 4; ++ct) {
            float bv = bias[(w * 4 + ct) * 16 + (lane & 15)];
            #pragma unroll
            for (int rt = 0; rt < 4; ++rt) {
                acc[rt][ct][0] = bv; acc[rt][ct][1] = bv;
                acc[rt][ct][2] = bv; acc[rt][ct][3] = bv;
            }
        }
        #pragma unroll 1
        for (int kt = 0; kt < 8; ++kt) {
            bf16x8 bfr[4];
            #pragma unroll
            for (int ct = 0; ct < 4; ++ct)
                bfr[ct] = *reinterpret_cast<const bf16x8*>(Wp + (((size_t)(w * 4 + ct) * 8 + kt) * 64 + lane) * 8);
            #pragma unroll
            for (int rt = 0; rt < 4; ++rt) {
                bf16x8 a = *reinterpret_cast<const bf16x8*>(buf + ((rt * 8 + kt) * 64 + swl) * 8);
                #pragma unroll
                for (int ct = 0; ct < 4; ++ct)
                    acc[rt][ct] = __builtin_amdgcn_mfma_f32_16x16x32_bf16(a, bfr[ct], acc[rt][ct], 0, 0, 0);
            }
        }
        __syncthreads();
    }
    // store layer-4 acts
    #pragma unroll
    for (int rt = 0; rt < 4; ++rt)
        #pragma unroll
        for (int ct = 0; ct < 4; ++ct) {
            int col = (w * 4 + ct) * 16 + (lane & 15);
            int kt = col >> 5;
            int chk = (col & 31) >> 3;
            #pragma unroll
            for (int j = 0; j < 4; ++j) {
                int rowm = ((lane >> 4) << 2) + j;
                int slot = rowm + (chk << 4);
                int sw = slot ^ ((slot >> 3) & 3);
                buf[((rt * 8 + kt) * 64 + sw) * 8 + (col & 7)] =
                    f2bf(fmaxf(acc[rt][ct][j], 0.0f));
            }
        }
    __syncthreads();

    // ---------------- layer 5: 256 -> 1 (wave w handles row-tile w) ----------------
    {
        float b4v = b4[0];
        f32x4 a5;
        a5[0] = b4v; a5[1] = b4v; a5[2] = b4v; a5[3] = b4v;
        #pragma unroll
        for (int kt = 0; kt < 8; ++kt) {
            bf16x8 bb = *reinterpret_cast<const bf16x8*>(W4p + ((size_t)kt * 64 + lane) * 8);
            bf16x8 aa = *reinterpret_cast<const bf16x8*>(buf + ((w * 8 + kt) * 64 + swl) * 8);
            a5 = __builtin_amdgcn_mfma_f32_16x16x32_bf16(aa, bb, a5, 0, 0, 0);
        }
        if ((lane & 15) == 0) {
            #pragma unroll
            for (int j = 0; j < 4; ++j)
                pred_lds[w * 16 + ((lane >> 4) << 2) + j] = a5[j];
        }
    }
    __syncthreads();

    // ---------------- local-ensemble combine (diagonal area swap) ----------------
    if (t < 16) {
        int oq = blockIdx.x * 16 + t;
        float p0 = pred_lds[t * 4 + 0], p1 = pred_lds[t * 4 + 1];
        float p2 = pred_lds[t * 4 + 2], p3 = pred_lds[t * 4 + 3];
        float a0 = area_lds[t * 4 + 0], a1 = area_lds[t * 4 + 1];
        float a2 = area_lds[t * 4 + 2], a3 = area_lds[t * 4 + 3];
        float tot = a0 + a1 + a2 + a3;
        out[oq] = (p0 * a3 + p1 * a2 + p2 * a1 + p3 * a0) / tot;
    }
}

extern "C" void kernel_launch(void* const* d_in, const int* in_sizes, int n_in,
                              void* d_out, int out_size, void* d_ws, size_t ws_size,
                              hipStream_t stream) {
    const float* feat  = (const float*)d_in[0];
    const float* coord = (const float*)d_in[1];
    const float* cell  = (const float*)d_in[2];
    const float* W0 = (const float*)d_in[3];
    const float* b0 = (const float*)d_in[4];
    const float* W1 = (const float*)d_in[5];
    const float* b1 = (const float*)d_in[6];
    const float* W2 = (const float*)d_in[7];
    const float* b2 = (const float*)d_in[8];
    const float* W3 = (const float*)d_in[9];
    const float* b3 = (const float*)d_in[10];
    const float* W4 = (const float*)d_in[11];
    const float* b4 = (const float*)d_in[12];
    float* out = (float*)d_out;

    ushort* featT = (ushort*)d_ws;          // 2*96*96*64      = 1179648 elems
    ushort* W0p = featT + 1179648;          // 16*19*64*8      = 155648
    ushort* W1p = W0p + 155648;             // 16*8*64*8       = 65536
    ushort* W2p = W1p + 65536;
    ushort* W3p = W2p + 65536;
    ushort* W4p = W3p + 65536;              // 1*8*64*8        = 4096

    prep_feat_k<<<4608, 256, 0, stream>>>(feat, featT);
    prep_w_k<<<76, 256, 0, stream>>>(W0, W0p, 16, 19, 256, 0);
    prep_w_k<<<32, 256, 0, stream>>>(W1, W1p, 16, 8, 256, 1);
    prep_w_k<<<32, 256, 0, stream>>>(W2, W2p, 16, 8, 256, 1);
    prep_w_k<<<32, 256, 0, stream>>>(W3, W3p, 16, 8, 256, 1);
    prep_w_k<<<2, 256, 0, stream>>>(W4, W4p, 1, 8, 1, 2);
    liif_main<<<4096, 256, 0, stream>>>(coord, cell, featT, W0p, W1p, W2p, W3p, W4p,
                                        b0, b1, b2, b3, b4, out);
}

// Round 5
// 206.815 us; speedup vs baseline: 1.4035x; 1.1012x over previous
//
#include <hip/hip_runtime.h>
#include <hip/hip_bf16.h>

typedef __attribute__((ext_vector_type(8))) short bf16x8;
typedef __attribute__((ext_vector_type(4))) float f32x4;

__device__ inline ushort f2bf(float f) {
    union { float f; unsigned u; } x; x.f = f;
    unsigned u = x.u;
    u += 0x7fffu + ((u >> 16) & 1u);   // round-to-nearest-even
    return (ushort)(u >> 16);
}

// feat (B,C,H,W) f32 -> featT (B,98,98,C) bf16, zero-padded 1-px border
__global__ void prep_feat_k(const float* __restrict__ feat, ushort* __restrict__ featT) {
    int idx = blockIdx.x * 256 + threadIdx.x;
    if (idx >= 2 * 98 * 98 * 64) return;
    int c = idx & 63;
    int rest = idx >> 6;
    int x = rest % 98; rest /= 98;
    int y = rest % 98;
    int b = rest / 98;
    ushort v = 0;
    if (x >= 1 && x <= 96 && y >= 1 && y <= 96)
        v = f2bf(feat[((b * 64 + c) * 96 + (y - 1)) * 96 + (x - 1)]);
    featT[idx] = v;
}

// Weights f32 (K,N) -> bf16 B-fragment layout [nt][kt][lane][8]
// mode 0: layer-1 with k-permutation (k = tap*64+c <- src row c*9+tap), K=580 pad 608
// mode 1: plain K=256
// mode 2: W4 (256,1), N padded to 16 (cols 1..15 zero)
__global__ void prep_w_k(const float* __restrict__ W, ushort* __restrict__ Wp,
                         int NT, int NKT, int Nstride, int mode) {
    int idx = blockIdx.x * 256 + threadIdx.x;
    if (idx >= NT * NKT * 64) return;
    int lane = idx & 63;
    int kt = (idx >> 6) % NKT;
    int nt = idx / (64 * NKT);
    int n = nt * 16 + (lane & 15);
    int kbase = kt * 32 + (lane >> 4) * 8;
    ushort o[8];
    #pragma unroll
    for (int i = 0; i < 8; ++i) {
        int k = kbase + i;
        float v = 0.0f;
        if (mode == 0) {
            if (k < 576) { int tap = k >> 6, c = k & 63; v = W[(c * 9 + tap) * Nstride + n]; }
            else if (k < 580) v = W[k * Nstride + n];
        } else if (mode == 1) {
            v = W[k * Nstride + n];
        } else {
            v = (n == 0) ? W[k] : 0.0f;
        }
        o[i] = f2bf(v);
    }
    *reinterpret_cast<uint4*>(Wp + (size_t)idx * 8) = *reinterpret_cast<const uint4*>(o);
}

// swizzle: sw = slot ^ (((slot>>3)&3)<<2)  (XOR into bits 2-3: doesn't disturb
// bits 0-1, so store_acts' 4 row-slots are a clean +16B stride; A-frag b128
// reads stay 2-way (free) on bank-quads)
__global__ __launch_bounds__(256, 3) void liif_main(
    const float* __restrict__ coord, const float* __restrict__ cell,
    const ushort* __restrict__ featT,
    const ushort* __restrict__ W0p, const ushort* __restrict__ W1p,
    const ushort* __restrict__ W2p, const ushort* __restrict__ W3p,
    const ushort* __restrict__ W4p,
    const float* __restrict__ b0, const float* __restrict__ b1,
    const float* __restrict__ b2, const float* __restrict__ b3,
    const float* __restrict__ b4, float* __restrict__ out)
{
    // act layout:   ((rt*8 + kt)*64 + sw)*8   rt 0..3, kt 0..7   (32768 B)
    // l1 chunk:     ((rt*8 + i )*64 + sw)*8   i = kt%8 per phase (same buffer)
    __shared__ ushort buf[4 * 8 * 64 * 8];
    __shared__ float pred_lds[64];
    __shared__ float area_lds[64];

    const int t = threadIdx.x;
    const int lane = t & 63;
    const int w = t >> 6;
    const int g = lane >> 4;
    const int l15 = lane & 15;
    const int swl = lane ^ (((lane >> 3) & 3) << 2);

    // ---------------- per-thread gather setup (4 threads per row) ----------------
    const int r = t >> 2, sub = t & 3;          // r 0..63
    const int qi = r >> 2, s = r & 3;           // row = 4*qi + shift s
    const int gq = blockIdx.x * 16 + qi;        // = b*Q + q
    const int bidx = gq >> 15;                  // Q = 32768
    int iy, ix;
    float rel0, rel1, rc0, rc1;
    {
        const float vx = (s & 2) ? 1.0f : -1.0f;
        const float vy = (s & 1) ? 1.0f : -1.0f;
        const float rxf = (float)(1.0 / 96.0);
        const float lo = (float)(-1.0 + 1e-6);
        const float hi = (float)(1.0 - 1e-6);
        float c0 = coord[gq * 2 + 0], c1 = coord[gq * 2 + 1];
        float cl0 = cell[gq * 2 + 0], cl1 = cell[gq * 2 + 1];
        float sc0 = fminf(fmaxf(__fadd_rn(__fadd_rn(c0, vx * rxf), 1e-6f), lo), hi);
        float sc1 = fminf(fmaxf(__fadd_rn(__fadd_rn(c1, vy * rxf), 1e-6f), lo), hi);
        float fy = __fmul_rn(__fadd_rn(__fmul_rn(__fadd_rn(sc0, 1.0f), 96.0f), -1.0f), 0.5f);
        float fx = __fmul_rn(__fadd_rn(__fmul_rn(__fadd_rn(sc1, 1.0f), 96.0f), -1.0f), 0.5f);
        iy = (int)rintf(fy); iy = iy < 0 ? 0 : (iy > 95 ? 95 : iy);
        ix = (int)rintf(fx); ix = ix < 0 ? 0 : (ix > 95 ? 95 : ix);
        float qc0 = (iy + 0.5f) * (float)(2.0 / 96.0) - 1.0f;
        float qc1 = (ix + 0.5f) * (float)(2.0 / 96.0) - 1.0f;
        rel0 = (c0 - qc0) * 96.0f;
        rel1 = (c1 - qc1) * 96.0f;
        rc0 = cl0 * 96.0f; rc1 = cl1 * 96.0f;
        if (sub == 0) area_lds[r] = fabsf(rel0 * rel1) + 1e-9f;
    }
    const int g_rt = r >> 4;
    const int g_slot = (r & 15) + (sub << 4);
    const int g_sw = g_slot ^ (((g_slot >> 3) & 3) << 2);
    // padded feat base: tap (ky,kj) -> +((ky*98+kj)*64), no bounds checks
    const ushort* p0 = featT + (size_t)bidx * 98 * 98 * 64 + (iy * 98 + ix) * 64 + sub * 8;

    // store-pointer precompute (layer-invariant): 4 col-tiles per wave
    ushort* sp[4];
    #pragma unroll
    for (int ct = 0; ct < 4; ++ct) {
        int col = (w * 4 + ct) * 16 + l15;
        int ktc = col >> 5;
        int chk = (col & 31) >> 3;
        int slot0 = (chk << 4) + g * 4;
        int sw0 = slot0 ^ (((slot0 >> 3) & 3) << 2);
        sp[ct] = buf + (ktc * 64 + sw0) * 8 + (col & 7);
    }

    f32x4 acc[4][4];

    auto store_acts = [&]() {
        #pragma unroll
        for (int ct = 0; ct < 4; ++ct)
            #pragma unroll
            for (int rt = 0; rt < 4; ++rt) {
                float v0 = fmaxf(acc[rt][ct][0], 0.0f);
                float v1 = fmaxf(acc[rt][ct][1], 0.0f);
                float v2 = fmaxf(acc[rt][ct][2], 0.0f);
                float v3 = fmaxf(acc[rt][ct][3], 0.0f);
                uint p01, p23;
                asm("v_cvt_pk_bf16_f32 %0, %1, %2" : "=v"(p01) : "v"(v0), "v"(v1));
                asm("v_cvt_pk_bf16_f32 %0, %1, %2" : "=v"(p23) : "v"(v2), "v"(v3));
                ushort* sptr = sp[ct] + rt * 4096;
                sptr[0]  = (ushort)p01;
                sptr[8]  = (ushort)(p01 >> 16);
                sptr[16] = (ushort)p23;
                sptr[24] = (ushort)(p23 >> 16);
            }
    };

    auto init_acc = [&](const float* bias) {
        #pragma unroll
        for (int ct = 0; ct < 4; ++ct) {
            float bv = bias[(w * 4 + ct) * 16 + l15];
            #pragma unroll
            for (int rt = 0; rt < 4; ++rt) {
                acc[rt][ct][0] = bv; acc[rt][ct][1] = bv;
                acc[rt][ct][2] = bv; acc[rt][ct][3] = bv;
            }
        }
    };

    auto l1_mfma = [&](int kt, int line) {
        bf16x8 bfr[4];
        #pragma unroll
        for (int ct = 0; ct < 4; ++ct)
            bfr[ct] = *reinterpret_cast<const bf16x8*>(W0p + (((size_t)(w * 4 + ct) * 19 + kt) * 64 + lane) * 8);
        #pragma unroll
        for (int rt = 0; rt < 4; ++rt) {
            bf16x8 a = *reinterpret_cast<const bf16x8*>(buf + ((rt * 8 + line) * 64 + swl) * 8);
            #pragma unroll
            for (int ct = 0; ct < 4; ++ct)
                acc[rt][ct] = __builtin_amdgcn_mfma_f32_16x16x32_bf16(a, bfr[ct], acc[rt][ct], 0, 0, 0);
        }
    };

    auto lx_mfma = [&](const ushort* Wp, int kt) {
        bf16x8 bfr[4];
        #pragma unroll
        for (int ct = 0; ct < 4; ++ct)
            bfr[ct] = *reinterpret_cast<const bf16x8*>(Wp + (((size_t)(w * 4 + ct) * 8 + kt) * 64 + lane) * 8);
        #pragma unroll
        for (int rt = 0; rt < 4; ++rt) {
            bf16x8 a = *reinterpret_cast<const bf16x8*>(buf + ((rt * 8 + kt) * 64 + swl) * 8);
            #pragma unroll
            for (int ct = 0; ct < 4; ++ct)
                acc[rt][ct] = __builtin_amdgcn_mfma_f32_16x16x32_bf16(a, bfr[ct], acc[rt][ct], 0, 0, 0);
        }
    };

#define G1(KT, LINE) do {                                                        \
        constexpr int tap_ = (KT) >> 1;                                          \
        constexpr int coff_ = ((tap_ / 3) * 98 + (tap_ % 3)) * 64 + ((KT) & 1) * 32; \
        *reinterpret_cast<uint4*>(&buf[((g_rt * 8 + (LINE)) * 64 + g_sw) * 8]) = \
            *reinterpret_cast<const uint4*>(p0 + coff_);                         \
    } while (0)

    // ---------------- layer 1: 3 phases (8 + 8 + 2+extras k-tiles) ----------------
    init_acc(b0);
    G1(0, 0); G1(1, 1); G1(2, 2); G1(3, 3); G1(4, 4); G1(5, 5); G1(6, 6); G1(7, 7);
    __syncthreads();
    __builtin_amdgcn_s_setprio(1);
    #pragma unroll 1
    for (int i = 0; i < 8; ++i) l1_mfma(i, i);
    __builtin_amdgcn_s_setprio(0);
    __syncthreads();
    G1(8, 0); G1(9, 1); G1(10, 2); G1(11, 3); G1(12, 4); G1(13, 5); G1(14, 6); G1(15, 7);
    __syncthreads();
    __builtin_amdgcn_s_setprio(1);
    #pragma unroll 1
    for (int i = 0; i < 8; ++i) l1_mfma(8 + i, i);
    __builtin_amdgcn_s_setprio(0);
    __syncthreads();
    G1(16, 0); G1(17, 1);
    {   // extras: rel0, rel1, rel_cell, zero-pad  (k-tile 18 -> line 2)
        ushort ex[8] = {0, 0, 0, 0, 0, 0, 0, 0};
        if (sub == 0) {
            ex[0] = f2bf(rel0); ex[1] = f2bf(rel1);
            ex[2] = f2bf(rc0);  ex[3] = f2bf(rc1);
        }
        *reinterpret_cast<uint4*>(&buf[((g_rt * 8 + 2) * 64 + g_sw) * 8]) =
            *reinterpret_cast<const uint4*>(ex);
    }
    __syncthreads();
    __builtin_amdgcn_s_setprio(1);
    l1_mfma(16, 0); l1_mfma(17, 1); l1_mfma(18, 2);
    __builtin_amdgcn_s_setprio(0);
    __syncthreads();

    // ---------------- layers 2..4: store -> own-kt mfma -> barrier -> rest ----------------
    #pragma unroll 1
    for (int layer = 0; layer < 3; ++layer) {
        store_acts();
        const ushort* Wp = (layer == 0) ? W1p : (layer == 1) ? W2p : W3p;
        const float* bias = (layer == 0) ? b1 : (layer == 1) ? b2 : b3;
        init_acc(bias);
        // own col-tiles provide A for kt = 2w, 2w+1: run before barrier (overlaps
        // other waves' stores; same-wave DS FIFO makes own write->read safe)
        __builtin_amdgcn_s_setprio(1);
        lx_mfma(Wp, 2 * w);
        lx_mfma(Wp, 2 * w + 1);
        __builtin_amdgcn_s_setprio(0);
        __syncthreads();
        __builtin_amdgcn_s_setprio(1);
        #pragma unroll 1
        for (int i = 2; i < 8; ++i) lx_mfma(Wp, (2 * w + i) & 7);
        __builtin_amdgcn_s_setprio(0);
        __syncthreads();
    }
    // layer-4 acts
    store_acts();
    __syncthreads();

    // ---------------- layer 5: 256 -> 1 (wave w handles row-tile w) ----------------
    {
        float b4v = b4[0];
        f32x4 a5;
        a5[0] = b4v; a5[1] = b4v; a5[2] = b4v; a5[3] = b4v;
        #pragma unroll
        for (int kt = 0; kt < 8; ++kt) {
            bf16x8 bb = *reinterpret_cast<const bf16x8*>(W4p + ((size_t)kt * 64 + lane) * 8);
            bf16x8 aa = *reinterpret_cast<const bf16x8*>(buf + ((w * 8 + kt) * 64 + swl) * 8);
            a5 = __builtin_amdgcn_mfma_f32_16x16x32_bf16(aa, bb, a5, 0, 0, 0);
        }
        if (l15 == 0) {
            #pragma unroll
            for (int j = 0; j < 4; ++j)
                pred_lds[w * 16 + (g << 2) + j] = a5[j];
        }
    }
    __syncthreads();

    // ---------------- local-ensemble combine (diagonal area swap) ----------------
    if (t < 16) {
        int oq = blockIdx.x * 16 + t;
        float p0v = pred_lds[t * 4 + 0], p1v = pred_lds[t * 4 + 1];
        float p2v = pred_lds[t * 4 + 2], p3v = pred_lds[t * 4 + 3];
        float a0 = area_lds[t * 4 + 0], a1 = area_lds[t * 4 + 1];
        float a2 = area_lds[t * 4 + 2], a3 = area_lds[t * 4 + 3];
        float tot = a0 + a1 + a2 + a3;
        out[oq] = (p0v * a3 + p1v * a2 + p2v * a1 + p3v * a0) / tot;
    }
#undef G1
}

extern "C" void kernel_launch(void* const* d_in, const int* in_sizes, int n_in,
                              void* d_out, int out_size, void* d_ws, size_t ws_size,
                              hipStream_t stream) {
    const float* feat  = (const float*)d_in[0];
    const float* coord = (const float*)d_in[1];
    const float* cell  = (const float*)d_in[2];
    const float* W0 = (const float*)d_in[3];
    const float* b0 = (const float*)d_in[4];
    const float* W1 = (const float*)d_in[5];
    const float* b1 = (const float*)d_in[6];
    const float* W2 = (const float*)d_in[7];
    const float* b2 = (const float*)d_in[8];
    const float* W3 = (const float*)d_in[9];
    const float* b3 = (const float*)d_in[10];
    const float* W4 = (const float*)d_in[11];
    const float* b4 = (const float*)d_in[12];
    float* out = (float*)d_out;

    ushort* featT = (ushort*)d_ws;          // 2*98*98*64      = 1229312 elems
    ushort* W0p = featT + 1229312;          // 16*19*64*8      = 155648
    ushort* W1p = W0p + 155648;             // 16*8*64*8       = 65536
    ushort* W2p = W1p + 65536;
    ushort* W3p = W2p + 65536;
    ushort* W4p = W3p + 65536;              // 1*8*64*8        = 4096

    prep_feat_k<<<4802, 256, 0, stream>>>(feat, featT);
    prep_w_k<<<76, 256, 0, stream>>>(W0, W0p, 16, 19, 256, 0);
    prep_w_k<<<32, 256, 0, stream>>>(W1, W1p, 16, 8, 256, 1);
    prep_w_k<<<32, 256, 0, stream>>>(W2, W2p, 16, 8, 256, 1);
    prep_w_k<<<32, 256, 0, stream>>>(W3, W3p, 16, 8, 256, 1);
    prep_w_k<<<2, 256, 0, stream>>>(W4, W4p, 1, 8, 1, 2);
    liif_main<<<4096, 256, 0, stream>>>(coord, cell, featT, W0p, W1p, W2p, W3p, W4p,
                                        b0, b1, b2, b3, b4, out);
}